// Round 7
// baseline (376.132 us; speedup 1.0000x reference)
//
#include <hip/hip_runtime.h>

#define NN 100000
#define NE 640000

typedef unsigned int uint32;
typedef __attribute__((ext_vector_type(8))) short short8;
typedef __attribute__((ext_vector_type(4))) float f32x4;

static __device__ __forceinline__ ushort f2bf(float f) {
    uint32 u = __float_as_uint(f);
    u = (u + 0x7fffu + ((u >> 16) & 1u)) >> 16;
    return (ushort)u;
}
static __device__ __forceinline__ float bf2f(uint32 bits16) {
    return __uint_as_float(bits16 << 16);
}
static __device__ __forceinline__ uint32 pack2(float a, float b) {
    return (uint32)f2bf(a) | ((uint32)f2bf(b) << 16);
}

// ---------------- degree + histogram ----------------

__global__ void k_deg_hist(const int* __restrict__ dst, const float* __restrict__ ew,
                           float* __restrict__ deg, int* __restrict__ cnt, int E) {
    int e = blockIdx.x * blockDim.x + threadIdx.x;
    if (e < E) {
        int d = dst[e];
        atomicAdd(&deg[d], ew[e]);
        atomicAdd(&cnt[d], 1);
    }
}

// ---------------- exclusive scan over cnt[0..n) -> rp ----------------

__global__ void k_scan1(const int* __restrict__ cnt, int* __restrict__ rp,
                        int* __restrict__ bsum, int n) {
    __shared__ int tsum[256];
    const int base = blockIdx.x * 1024;
    const int t = threadIdx.x;
    int v[4], s = 0;
#pragma unroll
    for (int j = 0; j < 4; ++j) {
        int idx = base + t * 4 + j;
        v[j] = (idx < n) ? cnt[idx] : 0;
        s += v[j];
    }
    tsum[t] = s;
    __syncthreads();
    for (int off = 1; off < 256; off <<= 1) {
        int x = (t >= off) ? tsum[t - off] : 0;
        __syncthreads();
        tsum[t] += x;
        __syncthreads();
    }
    int excl = (t > 0) ? tsum[t - 1] : 0;
#pragma unroll
    for (int j = 0; j < 4; ++j) {
        int idx = base + t * 4 + j;
        if (idx < n) rp[idx] = excl;
        excl += v[j];
    }
    if (t == 255) bsum[blockIdx.x] = tsum[255];
}

__global__ void k_scan2(int* __restrict__ bsum, int nb) {
    __shared__ int sh[256];
    int t = threadIdx.x;
    sh[t] = (t < nb) ? bsum[t] : 0;
    __syncthreads();
    for (int off = 1; off < 256; off <<= 1) {
        int x = (t >= off) ? sh[t - off] : 0;
        __syncthreads();
        sh[t] += x;
        __syncthreads();
    }
    if (t < nb) bsum[t] = (t > 0) ? sh[t - 1] : 0;
}

// adds block offsets; initializes cursor = rp; computes dinv in place (fused)
__global__ void k_scan3(int* __restrict__ rp, const int* __restrict__ bsum,
                        int* __restrict__ cursor, float* __restrict__ deg, int n) {
    int i = blockIdx.x * blockDim.x + threadIdx.x;
    if (i < n) {
        int v = rp[i] + bsum[i >> 10];
        rp[i] = v;
        cursor[i] = v;
        float d = deg[i];
        deg[i] = (d > 0.f) ? rsqrtf(d) : 0.f;
    }
    if (i == 0) rp[n] = NE;
}

// ---------------- fill CSR buckets: ep[pos] = (src, norm) ----------------
__global__ void k_fill(const int* __restrict__ src, const int* __restrict__ dst,
                       const float* __restrict__ ew, const float* __restrict__ dinv,
                       int* __restrict__ cursor, uint2* __restrict__ ep, int E) {
    int e = blockIdx.x * blockDim.x + threadIdx.x;
    if (e < E) {
        int s = src[e], d = dst[e];
        int pos = atomicAdd(&cursor[d], 1);
        float nv = dinv[s] * ew[e] * dinv[d];
        ep[pos] = make_uint2((uint32)s, __float_as_uint(nv));
    }
}

// ---------------- shared device pieces ----------------

// stage W^T into LDS (bf16, swizzled) from fp32 row-major W[128][NOUT]
template <int NOUT, int THREADS>
static __device__ __forceinline__ void stage_W(const float* __restrict__ W,
                                               char* wt, int tid) {
#pragma unroll
    for (int i = 0; i < (NOUT * 16) / THREADS; ++i) {
        int id = tid + THREADS * i;
        int col = id >> 4, kb = id & 15;   // kb: 16B block along k (8 bf16)
        float v[8];
#pragma unroll
        for (int j = 0; j < 8; ++j) v[j] = W[(size_t)(kb * 8 + j) * NOUT + col];
        uint4 pk;
        pk.x = pack2(v[0], v[1]); pk.y = pack2(v[2], v[3]);
        pk.z = pack2(v[4], v[5]); pk.w = pack2(v[6], v[7]);
        *reinterpret_cast<uint4*>(wt + col * 256 + ((kb * 16) ^ ((col & 7) << 4))) = pk;
    }
}

// MFMA over a staged 128-row x 128-k A tile and NOUT-col B tile; store bf16 H
template <int NOUT>
static __device__ __forceinline__ void mfma_block(const char* xs, const char* wt,
                                                  ushort* __restrict__ H, int row0,
                                                  int N, int tid) {
    const int w = tid >> 6, lane = tid & 63;
    const int rl = w * 16 + (lane & 15);
    const int kg = lane >> 4;
    f32x4 acc[NOUT / 16];
#pragma unroll
    for (int ct = 0; ct < NOUT / 16; ++ct) acc[ct] = (f32x4){0.f, 0.f, 0.f, 0.f};
#pragma unroll
    for (int ks = 0; ks < 4; ++ks) {
        const int kb = ks * 64 + kg * 16;
        short8 a = *reinterpret_cast<const short8*>(xs + rl * 256 + (kb ^ ((rl & 7) << 4)));
#pragma unroll
        for (int ct = 0; ct < NOUT / 16; ++ct) {
            int col = ct * 16 + (lane & 15);
            short8 bfr = *reinterpret_cast<const short8*>(wt + col * 256 + (kb ^ ((col & 7) << 4)));
            acc[ct] = __builtin_amdgcn_mfma_f32_16x16x32_bf16(a, bfr, acc[ct], 0, 0, 0);
        }
    }
    // C/D layout: col=lane&15, row=(lane>>4)*4+reg (m89-verified)
#pragma unroll
    for (int ct = 0; ct < NOUT / 16; ++ct) {
        int col = ct * 16 + (lane & 15);
#pragma unroll
        for (int r = 0; r < 4; ++r) {
            int gr = row0 + w * 16 + (lane >> 4) * 4 + r;
            if (gr < N) H[(size_t)gr * NOUT + col] = f2bf(acc[ct][r]);
        }
    }
}

// ---------------- layer-1 GEMM: H(bf16) = X(f32->bf16) @ W ----------------
template <int NOUT>
__global__ __launch_bounds__(512) void k_gemm_mfma(const float* __restrict__ X,
                                                   const float* __restrict__ W,
                                                   ushort* __restrict__ H, int N) {
    __shared__ char smem[128 * 256 + NOUT * 256];
    char* xs = smem;
    char* wt = smem + 128 * 256;
    const int tid = threadIdx.x;
    const int row0 = blockIdx.x * 128;

    stage_W<NOUT, 512>(W, wt, tid);
#pragma unroll
    for (int i = 0; i < 8; ++i) {
        int id = tid + 512 * i;
        int r = id >> 5, c4 = id & 31;
        int gr = row0 + r;
        float4 v = make_float4(0.f, 0.f, 0.f, 0.f);
        if (gr < N) v = *reinterpret_cast<const float4*>(&X[(size_t)gr * 128 + c4 * 4]);
        uint2 pk;
        pk.x = pack2(v.x, v.y);
        pk.y = pack2(v.z, v.w);
        *reinterpret_cast<uint2*>(xs + r * 256 + ((c4 * 8) ^ ((r & 7) << 4))) = pk;
    }
    __syncthreads();
    mfma_block<NOUT>(xs, wt, H, row0, N, tid);
}

// ---------------- fused: out = relu(agg(Hin)+bias); Hout = bf16(out) @ W ----------------
// 8 waves x 16 nodes; per node: 4 edge-slots x 16 lanes (R5-proven agg scheme).
template <int NOUT, int RELU>
__global__ __launch_bounds__(512) void k_fused(const int* __restrict__ rp,
                                               const uint2* __restrict__ ep,
                                               const ushort* __restrict__ Hin,
                                               const float* __restrict__ bias,
                                               const float* __restrict__ W,
                                               float* __restrict__ outF,
                                               ushort* __restrict__ Hout, int N) {
    __shared__ char smem[128 * 256 + NOUT * 256];
    char* xs = smem;
    char* wt = smem + 128 * 256;
    const int tid = threadIdx.x;
    const int row0 = blockIdx.x * 128;

    stage_W<NOUT, 512>(W, wt, tid);

    const int w = tid >> 6, lane = tid & 63;
    const int slot = lane >> 4;   // 0..3
    const int l16 = lane & 15;    // feats l16*8 .. +7
    for (int i = 0; i < 16; ++i) {
        const int r = w * 16 + i;
        const int n = row0 + r;
        if (n >= N) break;  // wave-uniform
        const int e0 = rp[n], e1 = rp[n + 1];
        float a[8] = {};
        for (int e = e0 + slot; e < e1; e += 4) {
            uint2 p = ep[e];
            float wgt = __uint_as_float(p.y);
            uint4 hv = *reinterpret_cast<const uint4*>(&Hin[(size_t)p.x * 128 + l16 * 8]);
            a[0] = fmaf(wgt, bf2f(hv.x & 0xffffu), a[0]);
            a[1] = fmaf(wgt, bf2f(hv.x >> 16), a[1]);
            a[2] = fmaf(wgt, bf2f(hv.y & 0xffffu), a[2]);
            a[3] = fmaf(wgt, bf2f(hv.y >> 16), a[3]);
            a[4] = fmaf(wgt, bf2f(hv.z & 0xffffu), a[4]);
            a[5] = fmaf(wgt, bf2f(hv.z >> 16), a[5]);
            a[6] = fmaf(wgt, bf2f(hv.w & 0xffffu), a[6]);
            a[7] = fmaf(wgt, bf2f(hv.w >> 16), a[7]);
        }
#pragma unroll
        for (int j = 0; j < 8; ++j) {
            a[j] += __shfl_xor(a[j], 32);
            a[j] += __shfl_xor(a[j], 16);
        }
        if (lane < 16) {
            const float4 b0 = *reinterpret_cast<const float4*>(&bias[l16 * 8]);
            const float4 b1 = *reinterpret_cast<const float4*>(&bias[l16 * 8 + 4]);
            float o[8] = {a[0] + b0.x, a[1] + b0.y, a[2] + b0.z, a[3] + b0.w,
                          a[4] + b1.x, a[5] + b1.y, a[6] + b1.z, a[7] + b1.w};
            if (RELU) {
#pragma unroll
                for (int j = 0; j < 8; ++j) o[j] = fmaxf(o[j], 0.f);
            }
            float* op = &outF[(size_t)n * 128 + l16 * 8];
            *reinterpret_cast<float4*>(op) = make_float4(o[0], o[1], o[2], o[3]);
            *reinterpret_cast<float4*>(op + 4) = make_float4(o[4], o[5], o[6], o[7]);
            uint4 pk;
            pk.x = pack2(o[0], o[1]); pk.y = pack2(o[2], o[3]);
            pk.z = pack2(o[4], o[5]); pk.w = pack2(o[6], o[7]);
            *reinterpret_cast<uint4*>(xs + r * 256 + ((l16 * 16) ^ ((r & 7) << 4))) = pk;
        }
    }
    __syncthreads();
    mfma_block<NOUT>(xs, wt, Hout, row0, N, tid);
}

// ---------------- aggregate (D=64): 8 edge-slots x 8 lanes x 16B ----------------
template <int WAVES, int RELU>
__global__ void k_agg64(const int* __restrict__ rp, const uint2* __restrict__ ep,
                        const ushort* __restrict__ H, const float* __restrict__ b,
                        float* __restrict__ out, int N) {
    const int wave = threadIdx.x >> 6;
    const int lane = threadIdx.x & 63;
    const int n = blockIdx.x * WAVES + wave;
    if (n >= N) return;
    const int e0 = rp[n], e1 = rp[n + 1];
    const int slot = lane >> 3;   // 0..7
    const int l8 = lane & 7;      // feats l8*8 .. +7

    float a[8] = {};
    for (int e = e0 + slot; e < e1; e += 8) {
        uint2 p = ep[e];
        float w = __uint_as_float(p.y);
        uint4 hv = *reinterpret_cast<const uint4*>(&H[(size_t)p.x * 64 + l8 * 8]);
        a[0] = fmaf(w, bf2f(hv.x & 0xffffu), a[0]);
        a[1] = fmaf(w, bf2f(hv.x >> 16), a[1]);
        a[2] = fmaf(w, bf2f(hv.y & 0xffffu), a[2]);
        a[3] = fmaf(w, bf2f(hv.y >> 16), a[3]);
        a[4] = fmaf(w, bf2f(hv.z & 0xffffu), a[4]);
        a[5] = fmaf(w, bf2f(hv.z >> 16), a[5]);
        a[6] = fmaf(w, bf2f(hv.w & 0xffffu), a[6]);
        a[7] = fmaf(w, bf2f(hv.w >> 16), a[7]);
    }
#pragma unroll
    for (int j = 0; j < 8; ++j) {
        a[j] += __shfl_xor(a[j], 8);
        a[j] += __shfl_xor(a[j], 16);
        a[j] += __shfl_xor(a[j], 32);
    }
    if (lane < 8) {
        const float4 b0 = *reinterpret_cast<const float4*>(&b[l8 * 8]);
        const float4 b1 = *reinterpret_cast<const float4*>(&b[l8 * 8 + 4]);
        float4 o0 = make_float4(a[0] + b0.x, a[1] + b0.y, a[2] + b0.z, a[3] + b0.w);
        float4 o1 = make_float4(a[4] + b1.x, a[5] + b1.y, a[6] + b1.z, a[7] + b1.w);
        if (RELU) {
            o0.x = fmaxf(o0.x, 0.f); o0.y = fmaxf(o0.y, 0.f);
            o0.z = fmaxf(o0.z, 0.f); o0.w = fmaxf(o0.w, 0.f);
            o1.x = fmaxf(o1.x, 0.f); o1.y = fmaxf(o1.y, 0.f);
            o1.z = fmaxf(o1.z, 0.f); o1.w = fmaxf(o1.w, 0.f);
        }
        float* op = &out[(size_t)n * 64 + l8 * 8];
        *reinterpret_cast<float4*>(op) = o0;
        *reinterpret_cast<float4*>(op + 4) = o1;
    }
}

// ---------------- launch ----------------

extern "C" void kernel_launch(void* const* d_in, const int* in_sizes, int n_in,
                              void* d_out, int out_size, void* d_ws, size_t ws_size,
                              hipStream_t stream) {
    const float* x  = (const float*)d_in[0];
    const int*   ei = (const int*)d_in[1];
    const float* ew = (const float*)d_in[2];
    const float* W1 = (const float*)d_in[3];
    const float* b1 = (const float*)d_in[4];
    const float* W2 = (const float*)d_in[5];
    const float* b2 = (const float*)d_in[6];
    const float* W3 = (const float*)d_in[7];
    const float* b3 = (const float*)d_in[8];

    const int* src = ei;
    const int* dst = ei + NE;

    // ws layout (floats) — total 14,380,256 floats = 57.52 MB (R2-proven bound)
    float*  ws    = (float*)d_ws;
    float*  deg   = ws;                          // NN f (becomes dinv)
    int*    cnt   = (int*)(ws + NN);             // NN i (histogram -> cursor)
    int*    rp    = (int*)(ws + 2 * NN);         // NN+1 i
    int*    bsum  = (int*)(ws + 3 * NN + 64);    // 128 i
    uint2*  ep    = (uint2*)(ws + 3 * NN + 256); // NE uint2 (src, norm)
    ushort* h1    = (ushort*)(ws + 3 * NN + 256 + 2 * NE); // NN*128 bf16
    ushort* h2    = h1 + (size_t)NN * 128;                 // NN*128 bf16
    ushort* h3    = h1;                                    // NN*64 bf16 (aliases h1)

    float* out0 = (float*)d_out;                 // [NN,128]
    float* out1 = out0 + NN * 128;               // [NN,128]
    float* out2 = out1 + NN * 128;               // [NN,64]

    const int B = 256;
    const int NB_SCAN = (NN + 1023) / 1024;      // 98

    // CSR build (deg and cnt adjacent -> one memset)
    hipMemsetAsync(deg, 0, 2 * NN * sizeof(float), stream);
    k_deg_hist<<<(NE + B - 1) / B, B, 0, stream>>>(dst, ew, deg, cnt, NE);
    k_scan1<<<NB_SCAN, 256, 0, stream>>>(cnt, rp, bsum, NN);
    k_scan2<<<1, 256, 0, stream>>>(bsum, NB_SCAN);
    k_scan3<<<(NN + B - 1) / B, B, 0, stream>>>(rp, bsum, cnt, deg, NN);
    k_fill<<<(NE + B - 1) / B, B, 0, stream>>>(src, dst, ew, deg, cnt, ep, NE);

    const int GB = (NN + 127) / 128;             // 782

    // layer 1 GEMM: h1 = x @ W1
    k_gemm_mfma<128><<<GB, 512, 0, stream>>>(x, W1, h1, NN);
    // fused layer-1 agg + layer-2 GEMM: out0 = relu(agg(h1)+b1); h2 = out0 @ W2
    k_fused<128, 1><<<GB, 512, 0, stream>>>(rp, ep, h1, b1, W2, out0, h2, NN);
    // fused layer-2 agg + layer-3 GEMM: out1 = relu(agg(h2)+b2); h3 = out1 @ W3
    k_fused<64, 1><<<GB, 512, 0, stream>>>(rp, ep, h2, b2, W3, out1, h3, NN);
    // final aggregate: out2 = agg(h3) + b3
    k_agg64<4, 0><<<(NN + 3) / 4, 256, 0, stream>>>(rp, ep, h3, b3, out2, NN);
}

// Round 8
// 326.836 us; speedup vs baseline: 1.1508x; 1.1508x over previous
//
#include <hip/hip_runtime.h>

#define NN 100000
#define NE 640000

typedef unsigned int uint32;
typedef __attribute__((ext_vector_type(8))) short short8;
typedef __attribute__((ext_vector_type(4))) float f32x4;

static __device__ __forceinline__ ushort f2bf(float f) {
    uint32 u = __float_as_uint(f);
    u = (u + 0x7fffu + ((u >> 16) & 1u)) >> 16;
    return (ushort)u;
}
static __device__ __forceinline__ float bf2f(uint32 bits16) {
    return __uint_as_float(bits16 << 16);
}
static __device__ __forceinline__ uint32 pack2(float a, float b) {
    return (uint32)f2bf(a) | ((uint32)f2bf(b) << 16);
}

// ---------------- degree + histogram ----------------

__global__ void k_deg_hist(const int* __restrict__ dst, const float* __restrict__ ew,
                           float* __restrict__ deg, int* __restrict__ cnt, int E) {
    int e = blockIdx.x * blockDim.x + threadIdx.x;
    if (e < E) {
        int d = dst[e];
        atomicAdd(&deg[d], ew[e]);
        atomicAdd(&cnt[d], 1);
    }
}

// ---------------- exclusive scan over cnt[0..n) -> rp ----------------

__global__ void k_scan1(const int* __restrict__ cnt, int* __restrict__ rp,
                        int* __restrict__ bsum, int n) {
    __shared__ int tsum[256];
    const int base = blockIdx.x * 1024;
    const int t = threadIdx.x;
    int v[4], s = 0;
#pragma unroll
    for (int j = 0; j < 4; ++j) {
        int idx = base + t * 4 + j;
        v[j] = (idx < n) ? cnt[idx] : 0;
        s += v[j];
    }
    tsum[t] = s;
    __syncthreads();
    for (int off = 1; off < 256; off <<= 1) {
        int x = (t >= off) ? tsum[t - off] : 0;
        __syncthreads();
        tsum[t] += x;
        __syncthreads();
    }
    int excl = (t > 0) ? tsum[t - 1] : 0;
#pragma unroll
    for (int j = 0; j < 4; ++j) {
        int idx = base + t * 4 + j;
        if (idx < n) rp[idx] = excl;
        excl += v[j];
    }
    if (t == 255) bsum[blockIdx.x] = tsum[255];
}

__global__ void k_scan2(int* __restrict__ bsum, int nb) {
    __shared__ int sh[256];
    int t = threadIdx.x;
    sh[t] = (t < nb) ? bsum[t] : 0;
    __syncthreads();
    for (int off = 1; off < 256; off <<= 1) {
        int x = (t >= off) ? sh[t - off] : 0;
        __syncthreads();
        sh[t] += x;
        __syncthreads();
    }
    if (t < nb) bsum[t] = (t > 0) ? sh[t - 1] : 0;
}

// adds block offsets; initializes cursor = rp; computes dinv in place (fused)
__global__ void k_scan3(int* __restrict__ rp, const int* __restrict__ bsum,
                        int* __restrict__ cursor, float* __restrict__ deg, int n) {
    int i = blockIdx.x * blockDim.x + threadIdx.x;
    if (i < n) {
        int v = rp[i] + bsum[i >> 10];
        rp[i] = v;
        cursor[i] = v;
        float d = deg[i];
        deg[i] = (d > 0.f) ? rsqrtf(d) : 0.f;
    }
    if (i == 0) rp[n] = NE;
}

// ---------------- fill CSR buckets: ep[pos] = (src, norm) ----------------
__global__ void k_fill(const int* __restrict__ src, const int* __restrict__ dst,
                       const float* __restrict__ ew, const float* __restrict__ dinv,
                       int* __restrict__ cursor, uint2* __restrict__ ep, int E) {
    int e = blockIdx.x * blockDim.x + threadIdx.x;
    if (e < E) {
        int s = src[e], d = dst[e];
        int pos = atomicAdd(&cursor[d], 1);
        float nv = dinv[s] * ew[e] * dinv[d];
        ep[pos] = make_uint2((uint32)s, __float_as_uint(nv));
    }
}

// ---------------- MFMA GEMM: H(bf16) = X(f32->bf16) @ W(f32) ----------------
// 512 thr (8 waves), 128 rows x NOUT cols per block. K=128 fully staged, 1 barrier.
// W^T staged bf16 directly from fp32 W (no prep kernel). XOR-swizzled LDS.
template <int NOUT>
__global__ __launch_bounds__(512) void k_gemm_mfma(const float* __restrict__ X,
                                                   const float* __restrict__ W,
                                                   ushort* __restrict__ H, int N) {
    __shared__ char smem[128 * 256 + NOUT * 256];
    char* xs = smem;               // [128 rows][128 k] bf16, swizzled
    char* wt = smem + 128 * 256;   // [NOUT cols][128 k] bf16, swizzled
    const int tid = threadIdx.x;
    const int row0 = blockIdx.x * 128;

    // stage W^T (bf16) from fp32 row-major W[128][NOUT]
#pragma unroll
    for (int i = 0; i < (NOUT * 16) / 512; ++i) {
        int id = tid + 512 * i;
        int col = id >> 4, kb = id & 15;   // kb: 16B block along k (8 bf16)
        float v[8];
#pragma unroll
        for (int j = 0; j < 8; ++j) v[j] = W[(size_t)(kb * 8 + j) * NOUT + col];
        uint4 pk;
        pk.x = pack2(v[0], v[1]); pk.y = pack2(v[2], v[3]);
        pk.z = pack2(v[4], v[5]); pk.w = pack2(v[6], v[7]);
        *reinterpret_cast<uint4*>(wt + col * 256 + ((kb * 16) ^ ((col & 7) << 4))) = pk;
    }
    // stage X tile: 128 rows x 32 float4 chunks, convert to bf16
#pragma unroll
    for (int i = 0; i < 8; ++i) {
        int id = tid + 512 * i;
        int r = id >> 5, c4 = id & 31;
        int gr = row0 + r;
        float4 v = make_float4(0.f, 0.f, 0.f, 0.f);
        if (gr < N) v = *reinterpret_cast<const float4*>(&X[(size_t)gr * 128 + c4 * 4]);
        uint2 pk;
        pk.x = pack2(v.x, v.y);
        pk.y = pack2(v.z, v.w);
        *reinterpret_cast<uint2*>(xs + r * 256 + ((c4 * 8) ^ ((r & 7) << 4))) = pk;
    }
    __syncthreads();

    const int w = tid >> 6, lane = tid & 63;
    const int rl = w * 16 + (lane & 15);
    const int kg = lane >> 4;
    f32x4 acc[NOUT / 16];
#pragma unroll
    for (int ct = 0; ct < NOUT / 16; ++ct) acc[ct] = (f32x4){0.f, 0.f, 0.f, 0.f};

#pragma unroll
    for (int ks = 0; ks < 4; ++ks) {
        const int kb = ks * 64 + kg * 16;
        short8 a = *reinterpret_cast<const short8*>(xs + rl * 256 + (kb ^ ((rl & 7) << 4)));
#pragma unroll
        for (int ct = 0; ct < NOUT / 16; ++ct) {
            int col = ct * 16 + (lane & 15);
            short8 bfr = *reinterpret_cast<const short8*>(wt + col * 256 + (kb ^ ((col & 7) << 4)));
            acc[ct] = __builtin_amdgcn_mfma_f32_16x16x32_bf16(a, bfr, acc[ct], 0, 0, 0);
        }
    }
    // C/D layout: col=lane&15, row=(lane>>4)*4+reg (m89-verified)
#pragma unroll
    for (int ct = 0; ct < NOUT / 16; ++ct) {
        int col = ct * 16 + (lane & 15);
#pragma unroll
        for (int r = 0; r < 4; ++r) {
            int gr = row0 + w * 16 + (lane >> 4) * 4 + r;
            if (gr < N) H[(size_t)gr * NOUT + col] = f2bf(acc[ct][r]);
        }
    }
}

// ---------------- aggregate (D=128): 4 edge-slots x 16 lanes (R5-proven) ----------------
template <int WAVES, int RELU>
__global__ void k_agg128(const int* __restrict__ rp, const uint2* __restrict__ ep,
                         const ushort* __restrict__ H, const float* __restrict__ b,
                         float* __restrict__ out, int N) {
    const int wave = threadIdx.x >> 6;
    const int lane = threadIdx.x & 63;
    const int n = blockIdx.x * WAVES + wave;
    if (n >= N) return;
    const int e0 = rp[n], e1 = rp[n + 1];
    const int slot = lane >> 4;   // 0..3
    const int l16 = lane & 15;    // feats l16*8 .. +7

    float a[8] = {};
    for (int e = e0 + slot; e < e1; e += 4) {
        uint2 p = ep[e];
        float w = __uint_as_float(p.y);
        uint4 hv = *reinterpret_cast<const uint4*>(&H[(size_t)p.x * 128 + l16 * 8]);
        a[0] = fmaf(w, bf2f(hv.x & 0xffffu), a[0]);
        a[1] = fmaf(w, bf2f(hv.x >> 16), a[1]);
        a[2] = fmaf(w, bf2f(hv.y & 0xffffu), a[2]);
        a[3] = fmaf(w, bf2f(hv.y >> 16), a[3]);
        a[4] = fmaf(w, bf2f(hv.z & 0xffffu), a[4]);
        a[5] = fmaf(w, bf2f(hv.z >> 16), a[5]);
        a[6] = fmaf(w, bf2f(hv.w & 0xffffu), a[6]);
        a[7] = fmaf(w, bf2f(hv.w >> 16), a[7]);
    }
#pragma unroll
    for (int j = 0; j < 8; ++j) {
        a[j] += __shfl_xor(a[j], 32);
        a[j] += __shfl_xor(a[j], 16);
    }
    if (lane < 16) {
        const float4 b0 = *reinterpret_cast<const float4*>(&b[l16 * 8]);
        const float4 b1 = *reinterpret_cast<const float4*>(&b[l16 * 8 + 4]);
        float4 o0 = make_float4(a[0] + b0.x, a[1] + b0.y, a[2] + b0.z, a[3] + b0.w);
        float4 o1 = make_float4(a[4] + b1.x, a[5] + b1.y, a[6] + b1.z, a[7] + b1.w);
        if (RELU) {
            o0.x = fmaxf(o0.x, 0.f); o0.y = fmaxf(o0.y, 0.f);
            o0.z = fmaxf(o0.z, 0.f); o0.w = fmaxf(o0.w, 0.f);
            o1.x = fmaxf(o1.x, 0.f); o1.y = fmaxf(o1.y, 0.f);
            o1.z = fmaxf(o1.z, 0.f); o1.w = fmaxf(o1.w, 0.f);
        }
        float* op = &out[(size_t)n * 128 + l16 * 8];
        *reinterpret_cast<float4*>(op) = o0;
        *reinterpret_cast<float4*>(op + 4) = o1;
    }
}

// ---------------- aggregate (D=64): 8 edge-slots x 8 lanes (R5-proven) ----------------
template <int WAVES, int RELU>
__global__ void k_agg64(const int* __restrict__ rp, const uint2* __restrict__ ep,
                        const ushort* __restrict__ H, const float* __restrict__ b,
                        float* __restrict__ out, int N) {
    const int wave = threadIdx.x >> 6;
    const int lane = threadIdx.x & 63;
    const int n = blockIdx.x * WAVES + wave;
    if (n >= N) return;
    const int e0 = rp[n], e1 = rp[n + 1];
    const int slot = lane >> 3;   // 0..7
    const int l8 = lane & 7;      // feats l8*8 .. +7

    float a[8] = {};
    for (int e = e0 + slot; e < e1; e += 8) {
        uint2 p = ep[e];
        float w = __uint_as_float(p.y);
        uint4 hv = *reinterpret_cast<const uint4*>(&H[(size_t)p.x * 64 + l8 * 8]);
        a[0] = fmaf(w, bf2f(hv.x & 0xffffu), a[0]);
        a[1] = fmaf(w, bf2f(hv.x >> 16), a[1]);
        a[2] = fmaf(w, bf2f(hv.y & 0xffffu), a[2]);
        a[3] = fmaf(w, bf2f(hv.y >> 16), a[3]);
        a[4] = fmaf(w, bf2f(hv.z & 0xffffu), a[4]);
        a[5] = fmaf(w, bf2f(hv.z >> 16), a[5]);
        a[6] = fmaf(w, bf2f(hv.w & 0xffffu), a[6]);
        a[7] = fmaf(w, bf2f(hv.w >> 16), a[7]);
    }
#pragma unroll
    for (int j = 0; j < 8; ++j) {
        a[j] += __shfl_xor(a[j], 8);
        a[j] += __shfl_xor(a[j], 16);
        a[j] += __shfl_xor(a[j], 32);
    }
    if (lane < 8) {
        const float4 b0 = *reinterpret_cast<const float4*>(&b[l8 * 8]);
        const float4 b1 = *reinterpret_cast<const float4*>(&b[l8 * 8 + 4]);
        float4 o0 = make_float4(a[0] + b0.x, a[1] + b0.y, a[2] + b0.z, a[3] + b0.w);
        float4 o1 = make_float4(a[4] + b1.x, a[5] + b1.y, a[6] + b1.z, a[7] + b1.w);
        if (RELU) {
            o0.x = fmaxf(o0.x, 0.f); o0.y = fmaxf(o0.y, 0.f);
            o0.z = fmaxf(o0.z, 0.f); o0.w = fmaxf(o0.w, 0.f);
            o1.x = fmaxf(o1.x, 0.f); o1.y = fmaxf(o1.y, 0.f);
            o1.z = fmaxf(o1.z, 0.f); o1.w = fmaxf(o1.w, 0.f);
        }
        float* op = &out[(size_t)n * 64 + l8 * 8];
        *reinterpret_cast<float4*>(op) = o0;
        *reinterpret_cast<float4*>(op + 4) = o1;
    }
}

// ---------------- launch ----------------

extern "C" void kernel_launch(void* const* d_in, const int* in_sizes, int n_in,
                              void* d_out, int out_size, void* d_ws, size_t ws_size,
                              hipStream_t stream) {
    const float* x  = (const float*)d_in[0];
    const int*   ei = (const int*)d_in[1];
    const float* ew = (const float*)d_in[2];
    const float* W1 = (const float*)d_in[3];
    const float* b1 = (const float*)d_in[4];
    const float* W2 = (const float*)d_in[5];
    const float* b2 = (const float*)d_in[6];
    const float* W3 = (const float*)d_in[7];
    const float* b3 = (const float*)d_in[8];

    const int* src = ei;
    const int* dst = ei + NE;

    // ws layout
    float*  ws    = (float*)d_ws;
    float*  deg   = ws;                          // NN f (becomes dinv)
    int*    cnt   = (int*)(ws + NN);             // NN i (histogram -> cursor)
    int*    rp    = (int*)(ws + 2 * NN);         // NN+1 i
    int*    bsum  = (int*)(ws + 3 * NN + 64);    // 128 i
    uint2*  ep    = (uint2*)(ws + 3 * NN + 256); // NE uint2 (src, norm)
    ushort* h1    = (ushort*)(ws + 3 * NN + 256 + 2 * NE); // NN*128 bf16
    ushort* h2    = h1 + (size_t)NN * 128;                 // NN*128 bf16
    ushort* h3    = h1;                                    // NN*64 bf16 (aliases h1)

    float* out0 = (float*)d_out;                 // [NN,128]
    float* out1 = out0 + NN * 128;               // [NN,128]
    float* out2 = out1 + NN * 128;               // [NN,64]

    const int B = 256;
    const int NB_SCAN = (NN + 1023) / 1024;      // 98

    // CSR build (deg and cnt adjacent -> one memset)
    hipMemsetAsync(deg, 0, 2 * NN * sizeof(float), stream);
    k_deg_hist<<<(NE + B - 1) / B, B, 0, stream>>>(dst, ew, deg, cnt, NE);
    k_scan1<<<NB_SCAN, 256, 0, stream>>>(cnt, rp, bsum, NN);
    k_scan2<<<1, 256, 0, stream>>>(bsum, NB_SCAN);
    k_scan3<<<(NN + B - 1) / B, B, 0, stream>>>(rp, bsum, cnt, deg, NN);
    k_fill<<<(NE + B - 1) / B, B, 0, stream>>>(src, dst, ew, deg, cnt, ep, NE);

    const int GB = (NN + 127) / 128;             // 782

    // ----- layer 1 -----
    k_gemm_mfma<128><<<GB, 512, 0, stream>>>(x, W1, h1, NN);
    k_agg128<4, 1><<<(NN + 3) / 4, 256, 0, stream>>>(rp, ep, h1, b1, out0, NN);

    // ----- layer 2 -----
    k_gemm_mfma<128><<<GB, 512, 0, stream>>>(out0, W2, h2, NN);
    k_agg128<4, 1><<<(NN + 3) / 4, 256, 0, stream>>>(rp, ep, h2, b2, out1, NN);

    // ----- layer 3 -----
    k_gemm_mfma<64><<<GB, 512, 0, stream>>>(out1, W3, h3, NN);
    k_agg64<4, 0><<<(NN + 3) / 4, 256, 0, stream>>>(rp, ep, h3, b3, out2, NN);
}

// Round 9
// 281.051 us; speedup vs baseline: 1.3383x; 1.1629x over previous
//
#include <hip/hip_runtime.h>

#define NN 100000
#define NE 640000

typedef unsigned int uint32;
typedef __attribute__((ext_vector_type(8))) short short8;
typedef __attribute__((ext_vector_type(4))) float f32x4;

static __device__ __forceinline__ ushort f2bf(float f) {
    uint32 u = __float_as_uint(f);
    u = (u + 0x7fffu + ((u >> 16) & 1u)) >> 16;
    return (ushort)u;
}
static __device__ __forceinline__ float bf2f(uint32 bits16) {
    return __uint_as_float(bits16 << 16);
}
static __device__ __forceinline__ uint32 pack2(float a, float b) {
    return (uint32)f2bf(a) | ((uint32)f2bf(b) << 16);
}

// ---------------- degree + histogram ----------------

__global__ void k_deg_hist(const int* __restrict__ dst, const float* __restrict__ ew,
                           float* __restrict__ deg, int* __restrict__ cnt, int E) {
    int e = blockIdx.x * blockDim.x + threadIdx.x;
    if (e < E) {
        int d = dst[e];
        atomicAdd(&deg[d], ew[e]);
        atomicAdd(&cnt[d], 1);
    }
}

// ---------------- exclusive scan over cnt[0..n) -> rp ----------------

__global__ void k_scan1(const int* __restrict__ cnt, int* __restrict__ rp,
                        int* __restrict__ bsum, int n) {
    __shared__ int tsum[256];
    const int base = blockIdx.x * 1024;
    const int t = threadIdx.x;
    int v[4], s = 0;
#pragma unroll
    for (int j = 0; j < 4; ++j) {
        int idx = base + t * 4 + j;
        v[j] = (idx < n) ? cnt[idx] : 0;
        s += v[j];
    }
    tsum[t] = s;
    __syncthreads();
    for (int off = 1; off < 256; off <<= 1) {
        int x = (t >= off) ? tsum[t - off] : 0;
        __syncthreads();
        tsum[t] += x;
        __syncthreads();
    }
    int excl = (t > 0) ? tsum[t - 1] : 0;
#pragma unroll
    for (int j = 0; j < 4; ++j) {
        int idx = base + t * 4 + j;
        if (idx < n) rp[idx] = excl;
        excl += v[j];
    }
    if (t == 255) bsum[blockIdx.x] = tsum[255];
}

__global__ void k_scan2(int* __restrict__ bsum, int nb) {
    __shared__ int sh[256];
    int t = threadIdx.x;
    sh[t] = (t < nb) ? bsum[t] : 0;
    __syncthreads();
    for (int off = 1; off < 256; off <<= 1) {
        int x = (t >= off) ? sh[t - off] : 0;
        __syncthreads();
        sh[t] += x;
        __syncthreads();
    }
    if (t < nb) bsum[t] = (t > 0) ? sh[t - 1] : 0;
}

// adds block offsets; initializes cursor = rp; computes dinv in place (fused)
__global__ void k_scan3(int* __restrict__ rp, const int* __restrict__ bsum,
                        int* __restrict__ cursor, float* __restrict__ deg, int n) {
    int i = blockIdx.x * blockDim.x + threadIdx.x;
    if (i < n) {
        int v = rp[i] + bsum[i >> 10];
        rp[i] = v;
        cursor[i] = v;
        float d = deg[i];
        deg[i] = (d > 0.f) ? rsqrtf(d) : 0.f;
    }
    if (i == 0) rp[n] = NE;
}

// ---------------- fill CSR buckets: ep[pos] = (src, norm) ----------------
__global__ void k_fill(const int* __restrict__ src, const int* __restrict__ dst,
                       const float* __restrict__ ew, const float* __restrict__ dinv,
                       int* __restrict__ cursor, uint2* __restrict__ ep, int E) {
    int e = blockIdx.x * blockDim.x + threadIdx.x;
    if (e < E) {
        int s = src[e], d = dst[e];
        int pos = atomicAdd(&cursor[d], 1);
        float nv = dinv[s] * ew[e] * dinv[d];
        ep[pos] = make_uint2((uint32)s, __float_as_uint(nv));
    }
}

// ---------------- fused W prep: Wt[col][k] = bf16(W[k][col]) for all 3 ----------------
__global__ void k_prepW_all(const float* __restrict__ W1, const float* __restrict__ W2,
                            const float* __restrict__ W3, ushort* __restrict__ wt1,
                            ushort* __restrict__ wt2, ushort* __restrict__ wt3) {
    int o = blockIdx.x * blockDim.x + threadIdx.x;
    if (o < 16384) {
        int col = o >> 7, k = o & 127;
        wt1[o] = f2bf(W1[k * 128 + col]);
    } else if (o < 32768) {
        int oo = o - 16384;
        int col = oo >> 7, k = oo & 127;
        wt2[oo] = f2bf(W2[k * 128 + col]);
    } else if (o < 40960) {
        int oo = o - 32768;
        int col = oo >> 7, k = oo & 127;
        wt3[oo] = f2bf(W3[k * 64 + col]);
    }
}

// ---------------- MFMA GEMM: H(bf16) = X(f32->bf16) @ Wt(bf16) ----------------
// R5-proven: 256 thr (4 waves), 64 rows x NOUT cols. K=128 fully staged, 1 barrier.
// LDS XOR-swizzle: 16B-block index ^= (row&7) => conflict-free fragment reads.
template <int NOUT>
__global__ __launch_bounds__(256) void k_gemm_mfma(const float* __restrict__ X,
                                                   const ushort* __restrict__ Wt,
                                                   ushort* __restrict__ H, int N) {
    __shared__ char smem[64 * 256 + NOUT * 256];
    char* xs = smem;              // [64 rows][128 k] bf16, swizzled
    char* wt = smem + 64 * 256;   // [NOUT cols][128 k] bf16, swizzled
    const int tid = threadIdx.x;
    const int row0 = blockIdx.x * 64;

    // stage Wt (coalesced uint4 copy of pre-transposed bf16)
    const uint4* Wt4 = reinterpret_cast<const uint4*>(Wt);
#pragma unroll
    for (int i = 0; i < NOUT / 16; ++i) {
        int id = tid + 256 * i;
        int col = id >> 4, c4 = id & 15;
        uint4 v = Wt4[id];
        *reinterpret_cast<uint4*>(wt + col * 256 + ((c4 * 16) ^ ((col & 7) << 4))) = v;
    }
    // stage X tile: 64 rows x 32 float4 chunks, convert to bf16
#pragma unroll
    for (int i = 0; i < 8; ++i) {
        int id = tid + 256 * i;
        int r = id >> 5, c4 = id & 31;
        int gr = row0 + r;
        float4 v = make_float4(0.f, 0.f, 0.f, 0.f);
        if (gr < N) v = *reinterpret_cast<const float4*>(&X[(size_t)gr * 128 + c4 * 4]);
        uint2 pk;
        pk.x = pack2(v.x, v.y);
        pk.y = pack2(v.z, v.w);
        *reinterpret_cast<uint2*>(xs + r * 256 + ((c4 * 8) ^ ((r & 7) << 4))) = pk;
    }
    __syncthreads();

    const int w = tid >> 6, lane = tid & 63;
    const int rl = w * 16 + (lane & 15);   // A row (local)
    const int kg = lane >> 4;              // k-group 0..3
    f32x4 acc[NOUT / 16];
#pragma unroll
    for (int ct = 0; ct < NOUT / 16; ++ct) acc[ct] = (f32x4){0.f, 0.f, 0.f, 0.f};

#pragma unroll
    for (int ks = 0; ks < 4; ++ks) {
        const int kb = ks * 64 + kg * 16;
        short8 a = *reinterpret_cast<const short8*>(xs + rl * 256 + (kb ^ ((rl & 7) << 4)));
#pragma unroll
        for (int ct = 0; ct < NOUT / 16; ++ct) {
            int col = ct * 16 + (lane & 15);
            short8 bfr = *reinterpret_cast<const short8*>(wt + col * 256 + (kb ^ ((col & 7) << 4)));
            acc[ct] = __builtin_amdgcn_mfma_f32_16x16x32_bf16(a, bfr, acc[ct], 0, 0, 0);
        }
    }
    // C/D layout: col=lane&15, row=(lane>>4)*4+reg (m89-verified)
#pragma unroll
    for (int ct = 0; ct < NOUT / 16; ++ct) {
        int col = ct * 16 + (lane & 15);
#pragma unroll
        for (int r = 0; r < 4; ++r) {
            int gr = row0 + w * 16 + (lane >> 4) * 4 + r;
            if (gr < N) H[(size_t)gr * NOUT + col] = f2bf(acc[ct][r]);
        }
    }
}

// ---------------- aggregate (D=128): 4 edge-slots x 16 lanes (R5-proven) ----------------
template <int WAVES, int RELU>
__global__ void k_agg128(const int* __restrict__ rp, const uint2* __restrict__ ep,
                         const ushort* __restrict__ H, const float* __restrict__ b,
                         float* __restrict__ out, int N) {
    const int wave = threadIdx.x >> 6;
    const int lane = threadIdx.x & 63;
    const int n = blockIdx.x * WAVES + wave;
    if (n >= N) return;
    const int e0 = rp[n], e1 = rp[n + 1];
    const int slot = lane >> 4;   // 0..3
    const int l16 = lane & 15;    // feats l16*8 .. +7

    float a[8] = {};
    for (int e = e0 + slot; e < e1; e += 4) {
        uint2 p = ep[e];
        float w = __uint_as_float(p.y);
        uint4 hv = *reinterpret_cast<const uint4*>(&H[(size_t)p.x * 128 + l16 * 8]);
        a[0] = fmaf(w, bf2f(hv.x & 0xffffu), a[0]);
        a[1] = fmaf(w, bf2f(hv.x >> 16), a[1]);
        a[2] = fmaf(w, bf2f(hv.y & 0xffffu), a[2]);
        a[3] = fmaf(w, bf2f(hv.y >> 16), a[3]);
        a[4] = fmaf(w, bf2f(hv.z & 0xffffu), a[4]);
        a[5] = fmaf(w, bf2f(hv.z >> 16), a[5]);
        a[6] = fmaf(w, bf2f(hv.w & 0xffffu), a[6]);
        a[7] = fmaf(w, bf2f(hv.w >> 16), a[7]);
    }
#pragma unroll
    for (int j = 0; j < 8; ++j) {
        a[j] += __shfl_xor(a[j], 32);
        a[j] += __shfl_xor(a[j], 16);
    }
    if (lane < 16) {
        const float4 b0 = *reinterpret_cast<const float4*>(&b[l16 * 8]);
        const float4 b1 = *reinterpret_cast<const float4*>(&b[l16 * 8 + 4]);
        float4 o0 = make_float4(a[0] + b0.x, a[1] + b0.y, a[2] + b0.z, a[3] + b0.w);
        float4 o1 = make_float4(a[4] + b1.x, a[5] + b1.y, a[6] + b1.z, a[7] + b1.w);
        if (RELU) {
            o0.x = fmaxf(o0.x, 0.f); o0.y = fmaxf(o0.y, 0.f);
            o0.z = fmaxf(o0.z, 0.f); o0.w = fmaxf(o0.w, 0.f);
            o1.x = fmaxf(o1.x, 0.f); o1.y = fmaxf(o1.y, 0.f);
            o1.z = fmaxf(o1.z, 0.f); o1.w = fmaxf(o1.w, 0.f);
        }
        float* op = &out[(size_t)n * 128 + l16 * 8];
        *reinterpret_cast<float4*>(op) = o0;
        *reinterpret_cast<float4*>(op + 4) = o1;
    }
}

// ---------------- aggregate (D=64): 8 edge-slots x 8 lanes (R5-proven) ----------------
template <int WAVES, int RELU>
__global__ void k_agg64(const int* __restrict__ rp, const uint2* __restrict__ ep,
                        const ushort* __restrict__ H, const float* __restrict__ b,
                        float* __restrict__ out, int N) {
    const int wave = threadIdx.x >> 6;
    const int lane = threadIdx.x & 63;
    const int n = blockIdx.x * WAVES + wave;
    if (n >= N) return;
    const int e0 = rp[n], e1 = rp[n + 1];
    const int slot = lane >> 3;   // 0..7
    const int l8 = lane & 7;      // feats l8*8 .. +7

    float a[8] = {};
    for (int e = e0 + slot; e < e1; e += 8) {
        uint2 p = ep[e];
        float w = __uint_as_float(p.y);
        uint4 hv = *reinterpret_cast<const uint4*>(&H[(size_t)p.x * 64 + l8 * 8]);
        a[0] = fmaf(w, bf2f(hv.x & 0xffffu), a[0]);
        a[1] = fmaf(w, bf2f(hv.x >> 16), a[1]);
        a[2] = fmaf(w, bf2f(hv.y & 0xffffu), a[2]);
        a[3] = fmaf(w, bf2f(hv.y >> 16), a[3]);
        a[4] = fmaf(w, bf2f(hv.z & 0xffffu), a[4]);
        a[5] = fmaf(w, bf2f(hv.z >> 16), a[5]);
        a[6] = fmaf(w, bf2f(hv.w & 0xffffu), a[6]);
        a[7] = fmaf(w, bf2f(hv.w >> 16), a[7]);
    }
#pragma unroll
    for (int j = 0; j < 8; ++j) {
        a[j] += __shfl_xor(a[j], 8);
        a[j] += __shfl_xor(a[j], 16);
        a[j] += __shfl_xor(a[j], 32);
    }
    if (lane < 8) {
        const float4 b0 = *reinterpret_cast<const float4*>(&b[l8 * 8]);
        const float4 b1 = *reinterpret_cast<const float4*>(&b[l8 * 8 + 4]);
        float4 o0 = make_float4(a[0] + b0.x, a[1] + b0.y, a[2] + b0.z, a[3] + b0.w);
        float4 o1 = make_float4(a[4] + b1.x, a[5] + b1.y, a[6] + b1.z, a[7] + b1.w);
        if (RELU) {
            o0.x = fmaxf(o0.x, 0.f); o0.y = fmaxf(o0.y, 0.f);
            o0.z = fmaxf(o0.z, 0.f); o0.w = fmaxf(o0.w, 0.f);
            o1.x = fmaxf(o1.x, 0.f); o1.y = fmaxf(o1.y, 0.f);
            o1.z = fmaxf(o1.z, 0.f); o1.w = fmaxf(o1.w, 0.f);
        }
        float* op = &out[(size_t)n * 64 + l8 * 8];
        *reinterpret_cast<float4*>(op) = o0;
        *reinterpret_cast<float4*>(op + 4) = o1;
    }
}

// ---------------- launch ----------------

extern "C" void kernel_launch(void* const* d_in, const int* in_sizes, int n_in,
                              void* d_out, int out_size, void* d_ws, size_t ws_size,
                              hipStream_t stream) {
    const float* x  = (const float*)d_in[0];
    const int*   ei = (const int*)d_in[1];
    const float* ew = (const float*)d_in[2];
    const float* W1 = (const float*)d_in[3];
    const float* b1 = (const float*)d_in[4];
    const float* W2 = (const float*)d_in[5];
    const float* b2 = (const float*)d_in[6];
    const float* W3 = (const float*)d_in[7];
    const float* b3 = (const float*)d_in[8];

    const int* src = ei;
    const int* dst = ei + NE;

    // ws layout
    float*  ws    = (float*)d_ws;
    float*  deg   = ws;                          // NN f (becomes dinv)
    int*    cnt   = (int*)(ws + NN);             // NN i (histogram -> cursor)
    int*    rp    = (int*)(ws + 2 * NN);         // NN+1 i
    int*    bsum  = (int*)(ws + 3 * NN + 64);    // 128 i
    uint2*  ep    = (uint2*)(ws + 3 * NN + 256); // NE uint2 (src, norm)
    ushort* h1    = (ushort*)(ws + 3 * NN + 256 + 2 * NE); // NN*128 bf16
    ushort* h2    = h1 + (size_t)NN * 128;                 // NN*128 bf16
    ushort* h3    = h1;                                    // NN*64 bf16 (aliases h1)
    ushort* wt1   = h2 + (size_t)NN * 128;       // 128*128 bf16 (W1^T)
    ushort* wt2   = wt1 + 128 * 128;             // 128*128 bf16
    ushort* wt3   = wt2 + 128 * 128;             // 64*128 bf16

    float* out0 = (float*)d_out;                 // [NN,128]
    float* out1 = out0 + NN * 128;               // [NN,128]
    float* out2 = out1 + NN * 128;               // [NN,64]

    const int B = 256;
    const int NB_SCAN = (NN + 1023) / 1024;      // 98

    // weight prep (one fused kernel)
    k_prepW_all<<<(40960 + B - 1) / B, B, 0, stream>>>(W1, W2, W3, wt1, wt2, wt3);

    // CSR build (deg and cnt adjacent -> one memset)
    hipMemsetAsync(deg, 0, 2 * NN * sizeof(float), stream);
    k_deg_hist<<<(NE + B - 1) / B, B, 0, stream>>>(dst, ew, deg, cnt, NE);
    k_scan1<<<NB_SCAN, 256, 0, stream>>>(cnt, rp, bsum, NN);
    k_scan2<<<1, 256, 0, stream>>>(bsum, NB_SCAN);
    k_scan3<<<(NN + B - 1) / B, B, 0, stream>>>(rp, bsum, cnt, deg, NN);
    k_fill<<<(NE + B - 1) / B, B, 0, stream>>>(src, dst, ew, deg, cnt, ep, NE);

    const int GB = (NN + 63) / 64;               // 1563

    // ----- layer 1 -----
    k_gemm_mfma<128><<<GB, 256, 0, stream>>>(x, wt1, h1, NN);
    k_agg128<4, 1><<<(NN + 3) / 4, 256, 0, stream>>>(rp, ep, h1, b1, out0, NN);

    // ----- layer 2 -----
    k_gemm_mfma<128><<<GB, 256, 0, stream>>>(out0, wt2, h2, NN);
    k_agg128<4, 1><<<(NN + 3) / 4, 256, 0, stream>>>(rp, ep, h2, b2, out1, NN);

    // ----- layer 3 -----
    k_gemm_mfma<64><<<GB, 256, 0, stream>>>(out1, wt3, h3, NN);
    k_agg64<4, 0><<<(NN + 3) / 4, 256, 0, stream>>>(rp, ep, h3, b3, out2, NN);
}